// Round 3
// baseline (161.595 us; speedup 1.0000x reference)
//
#include <hip/hip_runtime.h>
#include <hip/hip_bf16.h>

#define SQRT2f 1.41421356237309515f
#define SQRT3f 1.73205080756887729f

__device__ __forceinline__ float2 cmul(float2 a, float2 b) {
  return make_float2(a.x*b.x - a.y*b.y, a.x*b.y + a.y*b.x);
}

// ---- gate bodies (S = stride of the acted-on mode pair / mode) ----

// 9x9 beamsplitter expm(theta*BS_GEN), block-sparse closed form.
// p selects row-triple {0,1,2},{3,4,5},{6,7,8}. cs = (cos t, sin t).
template<int S>
__device__ __forceinline__ void bs_apply(const float2* __restrict__ cur,
                                         float2* __restrict__ nxt,
                                         int base, int p, float2 cs) {
  const float c = cs.x, s = cs.y;
  const float c2 = c*c - s*s, s2 = 2.f*c*s;
  const float cc = c*c, ss = s*s, rcs = SQRT2f*c*s;
  if (p == 0) {
    float2 a0 = cur[base];
    float2 a1 = cur[base+S],   a3 = cur[base+3*S];
    float2 a2 = cur[base+2*S], a4 = cur[base+4*S], a6 = cur[base+6*S];
    nxt[base]     = a0;
    nxt[base+S]   = make_float2(c*a1.x - s*a3.x, c*a1.y - s*a3.y);
    nxt[base+2*S] = make_float2(cc*a2.x - rcs*a4.x + ss*a6.x,
                                cc*a2.y - rcs*a4.y + ss*a6.y);
  } else if (p == 1) {
    float2 a1 = cur[base+S],   a3 = cur[base+3*S];
    float2 a2 = cur[base+2*S], a4 = cur[base+4*S], a6 = cur[base+6*S];
    float2 a5 = cur[base+5*S], a7 = cur[base+7*S];
    nxt[base+3*S] = make_float2(s*a1.x + c*a3.x, s*a1.y + c*a3.y);
    nxt[base+4*S] = make_float2(rcs*a2.x + c2*a4.x - rcs*a6.x,
                                rcs*a2.y + c2*a4.y - rcs*a6.y);
    nxt[base+5*S] = make_float2(c2*a5.x - s2*a7.x, c2*a5.y - s2*a7.y);
  } else {
    float2 a2 = cur[base+2*S], a4 = cur[base+4*S], a6 = cur[base+6*S];
    float2 a5 = cur[base+5*S], a7 = cur[base+7*S];
    float2 a8 = cur[base+8*S];
    nxt[base+6*S] = make_float2(ss*a2.x + rcs*a4.x + cc*a6.x,
                                ss*a2.y + rcs*a4.y + cc*a6.y);
    nxt[base+7*S] = make_float2(s2*a5.x + c2*a7.x, s2*a5.y + c2*a7.y);
    nxt[base+8*S] = a8;
  }
}

// displacement expm(r*(AD-A)); scv = (sw, cw) = (sin(√3 r)/√3, (1-cos(√3 r))/3)
template<int S>
__device__ __forceinline__ void disp_apply(const float2* __restrict__ cur,
                                           float2* __restrict__ nxt,
                                           int base, float2 scv) {
  const float sw = scv.x, cw = scv.y;
  float2 a = cur[base], b = cur[base+S], c = cur[base+2*S];
  const float u00 = 1.f-cw,     u01 = -sw,        u02 = SQRT2f*cw;
  const float u10 = sw,         u11 = 1.f-3.f*cw, u12 = -SQRT2f*sw;
  const float u20 = SQRT2f*cw,  u21 = SQRT2f*sw,  u22 = 1.f-2.f*cw;
  nxt[base]     = make_float2(u00*a.x+u01*b.x+u02*c.x, u00*a.y+u01*b.y+u02*c.y);
  nxt[base+S]   = make_float2(u10*a.x+u11*b.x+u12*c.x, u10*a.y+u11*b.y+u12*c.y);
  nxt[base+2*S] = make_float2(u20*a.x+u21*b.x+u22*c.x, u20*a.y+u21*b.y+u22*c.y);
}

// squeeze: rotation in (|0>,|2>) plane; CS = (cos(√2 t), sin(√2 t)), t=0.25*r
template<int S>
__device__ __forceinline__ void sq_apply(const float2* __restrict__ cur,
                                         float2* __restrict__ nxt,
                                         int base, float2 CS) {
  const float C = CS.x, Sn = CS.y;
  float2 a = cur[base], b = cur[base+S], c = cur[base+2*S];
  nxt[base]     = make_float2(C*a.x + Sn*c.x, C*a.y + Sn*c.y);
  nxt[base+S]   = b;
  nxt[base+2*S] = make_float2(-Sn*a.x + C*c.x, -Sn*a.y + C*c.y);
}

// diagonal phase: multiply n=1 element by p1, n=2 element by p2 (in place)
template<int S>
__device__ __forceinline__ void diag_apply(float2* __restrict__ cur,
                                           int base, float2 p1, float2 p2) {
  float2 b = cur[base+S];   cur[base+S]   = cmul(b, p1);
  float2 c = cur[base+2*S]; cur[base+2*S] = cmul(c, p2);
}

#define BASE4(g, s0,s1,s2,s3) ({ int _d=(g); int _b=(_d%3)*(s0); _d/=3; \
  _b += (_d%3)*(s1); _d/=3; _b += (_d%3)*(s2); _d/=3; _b += (_d%3)*(s3); _b; })
#define BASE5(g, s0,s1,s2,s3,s4) ({ int _d=(g); int _b=(_d%3)*(s0); _d/=3; \
  _b += (_d%3)*(s1); _d/=3; _b += (_d%3)*(s2); _d/=3; _b += (_d%3)*(s3); _d/=3; \
  _b += (_d%3)*(s4); _b; })

__global__ __launch_bounds__(256, 4)
void cvnn_kernel(const float* __restrict__ x,
                 const float* __restrict__ th1,
                 const float* __restrict__ th2,
                 const float* __restrict__ sr,
                 const float* __restrict__ dr,
                 const float* __restrict__ kp,
                 float* __restrict__ out) {
  __shared__ float2 psiA[729];
  __shared__ float2 psiB[729];
  __shared__ float2 scal[354];   // gate trig table
  __shared__ float red[24];

  const int tid = threadIdx.x;
  const int bidx = blockIdx.x;

  // ---- per-block gate scalar table (354 sincos total) ----
  // [0,180): BS (c,s); [180,216): SQ (C,S); [216,252): DISP (sw,cw);
  // [252,312): interferometer phases (c,s); [312,348): Kerr (c,s);
  // [348,354): initial displacement (sw,cw) from x[b,m]
  for (int f = tid; f < 354; f += 256) {
    float sn, cn; float2 v;
    if (f < 180) {
      int L = f/30, r = f%30, pass = r/15, n = r%15;
      float th = (pass ? th2 : th1)[L*35 + n];
      sincosf(th, &sn, &cn); v = make_float2(cn, sn);
    } else if (f < 216) {
      int i = f - 180;
      float a = 0.25f*SQRT2f*sr[i];
      sincosf(a, &sn, &cn); v = make_float2(cn, sn);
    } else if (f < 252) {
      int i = f - 216;
      float a = SQRT3f*dr[i];
      sincosf(a, &sn, &cn);
      v = make_float2(sn*(1.f/SQRT3f), (1.f-cn)*(1.f/3.f));
    } else if (f < 312) {
      int i = f - 252; int pl = i/5, mode = i%5; int L = pl/2, pass = pl%2;
      float phi = (pass ? th2 : th1)[L*35 + 29 + mode];
      sincosf(phi, &sn, &cn); v = make_float2(cn, sn);
    } else if (f < 348) {
      int i = f - 312;
      float kk = 0.001f*kp[i];
      sincosf(kk, &sn, &cn); v = make_float2(cn, sn);
    } else {
      int m = f - 348;
      float a = SQRT3f*x[bidx*6 + m];
      sincosf(a, &sn, &cn);
      v = make_float2(sn*(1.f/SQRT3f), (1.f-cn)*(1.f/3.f));
    }
    scal[f] = v;
  }
  __syncthreads();

  // ---- closed-form init: product state of displaced |0> columns ----
  for (int idx = tid; idx < 729; idx += 256) {
    float pr = 1.f; int d = idx;
#pragma unroll
    for (int mm = 5; mm >= 0; --mm) {
      int n = d % 3; d /= 3;
      float2 dc = scal[348 + mm];  // (sw, cw)
      float coef = (n == 0) ? (1.f - dc.y) : ((n == 1) ? dc.x : SQRT2f*dc.y);
      pr *= coef;
    }
    psiA[idx] = make_float2(pr, 0.f);
  }

  // ---- per-thread group bases ----
  const bool act = (tid < 243);
  const int p  = tid / 81;    // row-triple for BS gates
  const int g2 = tid % 81;
  // 2-mode gate: remaining-mode strides per pair k (pair stride = 3^(4-k))
  const int b20 = BASE4(g2, 1, 3, 9, 27);    // k=0, S=81
  const int b21 = BASE4(g2, 1, 3, 9, 243);   // k=1, S=27
  const int b22 = BASE4(g2, 1, 3, 81, 243);  // k=2, S=9
  const int b23 = BASE4(g2, 1, 27, 81, 243); // k=3, S=3
  const int b24 = BASE4(g2, 9, 27, 81, 243); // k=4, S=1
  // 1-mode gate: remaining strides per mode m (mode stride = 3^(5-m))
  const int b50 = BASE5(tid, 1, 3, 9, 27, 81);   // m=0, S=243
  const int b51 = BASE5(tid, 1, 3, 9, 27, 243);  // m=1, S=81
  const int b52 = BASE5(tid, 1, 3, 9, 81, 243);  // m=2, S=27
  const int b53 = BASE5(tid, 1, 3, 27, 81, 243); // m=3, S=9
  const int b54 = BASE5(tid, 1, 9, 27, 81, 243); // m=4, S=3
  const int b55 = BASE5(tid, 3, 9, 27, 81, 243); // m=5, S=1

  float2* cur = psiA;
  float2* nxt = psiB;
  __syncthreads();

#define SWAPBUF { float2* t__ = cur; cur = nxt; nxt = t__; }
#define BSG(SS, BASE, IDX) { if (act) bs_apply<SS>(cur, nxt, BASE, p, scal[IDX]); \
  __syncthreads(); SWAPBUF; }
#define DIAGG(SS, BASE, IDX) { if (act) { float2 p1_ = scal[IDX]; \
  float2 p2_ = cmul(p1_, p1_); diag_apply<SS>(cur, BASE, p1_, p2_); } __syncthreads(); }
#define SQG(SS, BASE, IDX) { if (act) sq_apply<SS>(cur, nxt, BASE, scal[IDX]); \
  __syncthreads(); SWAPBUF; }
#define DPG(SS, BASE, IDX) { if (act) disp_apply<SS>(cur, nxt, BASE, scal[IDX]); \
  __syncthreads(); SWAPBUF; }
#define KRG(SS, BASE, IDX) { if (act) { float2 p1_ = scal[IDX]; \
  float2 p2_ = cmul(p1_, p1_); float2 p4_ = cmul(p2_, p2_); \
  diag_apply<SS>(cur, BASE, p1_, p4_); } __syncthreads(); }

  for (int L = 0; L < 6; ++L) {
    for (int pass = 0; pass < 2; ++pass) {
      const int o = L*30 + pass*15;
      // beamsplitter ladder: k-sequence 0,2,4,1,3 repeated 3x
      BSG(81, b20, o+0);  BSG(9, b22, o+1);  BSG(1, b24, o+2);
      BSG(27, b21, o+3);  BSG(3, b23, o+4);
      BSG(81, b20, o+5);  BSG(9, b22, o+6);  BSG(1, b24, o+7);
      BSG(27, b21, o+8);  BSG(3, b23, o+9);
      BSG(81, b20, o+10); BSG(9, b22, o+11); BSG(1, b24, o+12);
      BSG(27, b21, o+13); BSG(3, b23, o+14);
      // interferometer output phases on modes 0..4
      const int po = 252 + (L*2 + pass)*5;
      DIAGG(243, b50, po+0); DIAGG(81, b51, po+1); DIAGG(27, b52, po+2);
      DIAGG(9,  b53, po+3);  DIAGG(3,  b54, po+4);
      if (pass == 0) {
        const int so = 180 + L*6;
        SQG(243, b50, so+0); SQG(81, b51, so+1); SQG(27, b52, so+2);
        SQG(9,  b53, so+3);  SQG(3,  b54, so+4); SQG(1,  b55, so+5);
      } else {
        const int dofs = 216 + L*6, ko = 312 + L*6;
        DPG(243, b50, dofs+0); KRG(243, b50, ko+0);
        DPG(81,  b51, dofs+1); KRG(81,  b51, ko+1);
        DPG(27,  b52, dofs+2); KRG(27,  b52, ko+2);
        DPG(9,   b53, dofs+3); KRG(9,   b53, ko+3);
        DPG(3,   b54, dofs+4); KRG(3,   b54, ko+4);
        DPG(1,   b55, dofs+5); KRG(1,   b55, ko+5);
      }
    }
  }

  // ---- <X_m> = sum over groups of 2Re(psi0* psi1) + 2*sqrt2*Re(psi1* psi2) ----
  const int lane = tid & 63, wid = tid >> 6;
#define XEXP(m, SS, BASE) { \
    float part = 0.f; \
    if (act) { \
      float2 a_ = cur[BASE]; float2 b_ = cur[(BASE)+(SS)]; float2 c_ = cur[(BASE)+2*(SS)]; \
      part = 2.f*(a_.x*b_.x + a_.y*b_.y) + 2.f*SQRT2f*(b_.x*c_.x + b_.y*c_.y); \
    } \
    for (int off = 32; off > 0; off >>= 1) part += __shfl_down(part, off); \
    if (lane == 0) red[(m)*4 + wid] = part; \
  }
  XEXP(0, 243, b50); XEXP(1, 81, b51); XEXP(2, 27, b52);
  XEXP(3, 9,  b53); XEXP(4, 3,  b54); XEXP(5, 1,  b55);
  __syncthreads();
  if (tid < 6) {
    float v = red[tid*4+0] + red[tid*4+1] + red[tid*4+2] + red[tid*4+3];
    out[bidx*6 + tid] = v;
  }
}

extern "C" void kernel_launch(void* const* d_in, const int* in_sizes, int n_in,
                              void* d_out, int out_size, void* d_ws, size_t ws_size,
                              hipStream_t stream) {
  const float* x  = (const float*)d_in[0];
  const float* t1 = (const float*)d_in[1];
  const float* t2 = (const float*)d_in[2];
  const float* sr = (const float*)d_in[3];
  const float* dr = (const float*)d_in[4];
  const float* kp = (const float*)d_in[5];
  const int B = in_sizes[0] / 6;
  cvnn_kernel<<<B, 256, 0, stream>>>(x, t1, t2, sr, dr, kp,
                                     (float*)d_out);
}